// Round 13
// baseline (627.573 us; speedup 1.0000x reference)
//
#include <hip/hip_runtime.h>

// LSTMPricePredictor: B=4096, T=512, IN=1, H=50, 2 layers + FC(50->1)
// R13 = R12 + (1) x tile staged in LDS (no global loads in loop -> the
//   per-iter `s_waitcnt vmcnt(0)` barrier straggler is gone; W_ih0*x folded
//   into EW as 4 FMAs, x-slot machinery deleted), (2) log2e folded into
//   weights/biases per gate (activations become bare v_exp_f32), (3)
//   shared-rcp EW: sig(i)*tanh(g) and sig(o)*tanh(c) each use ONE rcp ->
//   8 trans/cell (was 10). Overflow-safe: |gate| <= 14.4 by init bound.
// Structure = R11/R12 (both passed): 256 blocks (1/CU) x 832 threads
//   (13 waves); weights = A operand (row = 4*cell + gate), h = B operand
//   (N = batch = 16); D[row=4*quad+reg][col] => lane's 4 acc regs are
//   i,f,g,o of cell (4*wv+quad) for batch col; h double-buffered in LDS;
//   1 barrier/step.

typedef _Float16 half8 __attribute__((ext_vector_type(8)));
typedef float    f32x4 __attribute__((ext_vector_type(4)));

#define TT   512
#define HID  50
#define NB   16         // batch rows per block
#define LOG2E 1.44269504f

// Weight A-fragment: lane's 8 fp16 for K-chunk `chunk`, pre-scaled by the
// gate's exp2 factor. Row m -> gate = m&3, cell = 4*wv + (m>>2).
__device__ __forceinline__ float4 make_wfrag(const float* W, int gate, int cell,
                                             int chunk, int quad, float scale) {
    half8 hv = {};
    #pragma unroll
    for (int j = 0; j < 8; ++j) {
        const int k = 32 * chunk + 8 * quad + j;
        float v = 0.0f;
        if (cell < HID && k < HID) v = W[(gate * HID + cell) * HID + k] * scale;
        hv[j] = (_Float16)v;
    }
    return __builtin_bit_cast(float4, hv);
}

// Shared-rcp LSTM cell update on pre-scaled gates:
//   a0 = -i*log2e, a1 = -f*log2e, a2 = 2g*log2e, a3 = -o*log2e.
__device__ __forceinline__ float cell_update(const f32x4 a, float& c) {
    const float ei = __builtin_exp2f(a[0]);          // e^{-i}
    const float ef = __builtin_exp2f(a[1]);          // e^{-f}
    const float eg = __builtin_exp2f(a[2]);          // e^{2g}
    const float eo = __builtin_exp2f(a[3]);          // e^{-o}
    const float itg = (eg - 1.0f) *
        __builtin_amdgcn_rcpf((1.0f + ei) * (eg + 1.0f));   // sig(i)*tanh(g)
    const float sf = __builtin_amdgcn_rcpf(1.0f + ef);      // sig(f)
    c = sf * c + itg;
    const float ec = __builtin_exp2f(c * (2.0f * LOG2E));   // e^{2c}
    return (ec - 1.0f) *
        __builtin_amdgcn_rcpf((1.0f + eo) * (ec + 1.0f));   // sig(o)*tanh(c)
}

#define PIN(f) asm volatile("" : "+v"(f.x), "+v"(f.y), "+v"(f.z), "+v"(f.w));
#define MFMA(af, b, c) __builtin_amdgcn_mfma_f32_16x16x32_f16(__builtin_bit_cast(half8, (af)), (b), (c), 0, 0, 0)

extern "C" __global__ __launch_bounds__(832, 4)
void lstm2_mfma_kernel(const float* __restrict__ x,
                       const float* __restrict__ W_ih0, const float* __restrict__ W_hh0,
                       const float* __restrict__ b_ih0, const float* __restrict__ b_hh0,
                       const float* __restrict__ W_ih1, const float* __restrict__ W_hh1,
                       const float* __restrict__ b_ih1, const float* __restrict__ b_hh1,
                       const float* __restrict__ fc_w, const float* __restrict__ fc_b,
                       float* __restrict__ out)
{
    // h-state in B-fragment layout: element (k, n) at (k>>5)*512 +
    // (((k&31)>>3)*16 + n)*8 + (k&7), k<50 (rest pad = 0).
    __shared__ _Float16 H0[2][1024];
    __shared__ _Float16 H1[2][1024];
    __shared__ float    xs[NB * TT];      // staged x tile: xs[b][t] (32 KB)
    __shared__ float    hfin[HID * NB];   // fp32 h1^(TT) for the FC epilogue

    const int tid  = threadIdx.x;
    const int lane = tid & 63;
    const int wv   = tid >> 6;            // wave 0..12 = gate-row tile
    const int b0   = blockIdx.x * NB;

    for (int i = tid; i < 1024; i += 832) {
        H0[0][i] = (_Float16)0.f; H0[1][i] = (_Float16)0.f;
        H1[0][i] = (_Float16)0.f; H1[1][i] = (_Float16)0.f;
    }
    // stage x: block's slice is contiguous (NB*TT floats, 16B-aligned)
    {
        const float4* src = (const float4*)(x + (size_t)b0 * TT);
        float4* dst = (float4*)xs;
        for (int i = tid; i < NB * TT / 4; i += 832) dst[i] = src[i];
    }

    const int quad = lane >> 4;
    const int col  = lane & 15;           // batch column

    // ---- A-fragments (weights, exp2-prescaled), loaded once, pinned ----
    const int mrow  = lane & 15;
    const int gateA = mrow & 3;
    const int cellA = 4 * wv + (mrow >> 2);
    const float scA = (gateA == 2) ? 2.0f * LOG2E : -LOG2E;
    float4 A0c0 = make_wfrag(W_hh0, gateA, cellA, 0, quad, scA);
    float4 A0c1 = make_wfrag(W_hh0, gateA, cellA, 1, quad, scA);
    float4 Aic0 = make_wfrag(W_ih1, gateA, cellA, 0, quad, scA);
    float4 Aic1 = make_wfrag(W_ih1, gateA, cellA, 1, quad, scA);
    float4 Ahc0 = make_wfrag(W_hh1, gateA, cellA, 0, quad, scA);
    float4 Ahc1 = make_wfrag(W_hh1, gateA, cellA, 1, quad, scA);
    PIN(A0c0) PIN(A0c1) PIN(Aic0) PIN(Aic1) PIN(Ahc0) PIN(Ahc1)

    // ---- D-cell ownership: reg = gate, cell = 4*wv + quad, batch = col ----
    const int  cellD = 4 * wv + quad;
    const bool ewok  = (cellD < HID);
    f32x4 bias0, bias1, wx0;
    #pragma unroll
    for (int g = 0; g < 4; ++g) {
        const float s = (g == 2) ? 2.0f * LOG2E : -LOG2E;
        bias0[g] = ewok ? (b_ih0[g * HID + cellD] + b_hh0[g * HID + cellD]) * s : 0.f;
        bias1[g] = ewok ? (b_ih1[g * HID + cellD] + b_hh1[g * HID + cellD]) * s : 0.f;
        wx0[g]   = ewok ? W_ih0[g * HID + cellD] * s : 0.f;   // x rank-1 term
    }
    PIN(wx0)
    // h write-back index in B-layout for (cellD, col)
    const int wi = (cellD >> 5) * 512 + (((cellD & 31) >> 3) * 16 + col) * 8 + (cellD & 7);

    float c0 = 0.f, c1 = 0.f;
    __syncthreads();

    #pragma unroll 2
    for (int u = 0; u <= TT; ++u) {
        const int pu = u & 1, pn = pu ^ 1;

        half8 b0c0 = *(half8*)(&H0[pu][lane * 8]);
        half8 b0c1 = *(half8*)(&H0[pu][512 + lane * 8]);

        if (u != TT) {   // ---- layer-0: gates0^u + in-register EW ----
            const float xv = xs[col * TT + u];     // x_u for this batch col
            f32x4 acc = bias0;
            #pragma unroll
            for (int g = 0; g < 4; ++g) acc[g] += wx0[g] * xv;
            acc = MFMA(A0c0, b0c0, acc);
            acc = MFMA(A0c1, b0c1, acc);
            const float h = cell_update(acc, c0);
            if (ewok) H0[pn][wi] = (_Float16)h;    // h0^{u+1}
        }
        if (u != 0) {    // ---- layer-1: gates1^{u-1} + in-register EW ----
            half8 b1c0 = *(half8*)(&H1[pn][lane * 8]);
            half8 b1c1 = *(half8*)(&H1[pn][512 + lane * 8]);
            f32x4 acc = bias1;
            acc = MFMA(Aic0, b0c0, acc);           // Wi1 . h0^u
            acc = MFMA(Aic1, b0c1, acc);
            acc = MFMA(Ahc0, b1c0, acc);           // Wh1 . h1^{u-1}
            acc = MFMA(Ahc1, b1c1, acc);
            const float h = cell_update(acc, c1);
            if (ewok) {
                H1[pu][wi] = (_Float16)h;          // h1^u
                if (u == TT) hfin[cellD * NB + col] = h;
            }
        }
        __syncthreads();
    }

    // ---------- FC epilogue: out[b] = fc_b + fc_w . h1^(TT)[b,:] ----------
    if (tid < NB) {
        float s = fc_b[0];
        for (int k = 0; k < HID; ++k)
            s += fc_w[k] * hfin[k * NB + tid];
        out[b0 + tid] = s;
    }
}

extern "C" void kernel_launch(void* const* d_in, const int* in_sizes, int n_in,
                              void* d_out, int out_size, void* d_ws, size_t ws_size,
                              hipStream_t stream) {
    (void)in_sizes; (void)n_in; (void)d_ws; (void)ws_size; (void)out_size;
    const float* x     = (const float*)d_in[0];
    const float* W_ih0 = (const float*)d_in[1];
    const float* W_hh0 = (const float*)d_in[2];
    const float* b_ih0 = (const float*)d_in[3];
    const float* b_hh0 = (const float*)d_in[4];
    const float* W_ih1 = (const float*)d_in[5];
    const float* W_hh1 = (const float*)d_in[6];
    const float* b_ih1 = (const float*)d_in[7];
    const float* b_hh1 = (const float*)d_in[8];
    const float* fc_w  = (const float*)d_in[9];
    const float* fc_b  = (const float*)d_in[10];

    dim3 grid(4096 / NB);   // 256 blocks, 1 per CU
    dim3 block(832);        // 13 waves
    lstm2_mfma_kernel<<<grid, block, 0, stream>>>(
        x, W_ih0, W_hh0, b_ih0, b_hh0,
        W_ih1, W_hh1, b_ih1, b_hh1,
        fc_w, fc_b, (float*)d_out);
}

// Round 14
// 597.901 us; speedup vs baseline: 1.0496x; 1.0496x over previous
//
#include <hip/hip_runtime.h>

// LSTMPricePredictor: B=4096, T=512, IN=1, H=50, 2 layers + FC(50->1)
// R14 = R13 with the x-tile layout bug fixed.
//   R13 (607 us, REGRESSION vs R12's 447): xs[col*512+u] has row stride
//   512 floats = 0 mod 32 banks -> all 16 batch cols on ONE bank = 16-way
//   conflict on the critical path every step (SQ_LDS_BANK_CONFLICT 9x).
//   Fix: TRANSPOSED tile xs[t*16+b] -> 16 cols on 16 consecutive banks,
//   4 lanes broadcast-share each address, conflict-free; each step reads
//   one contiguous 64B line. Staging scatter happens once (negligible).
// Everything else identical to R13 (which = R12 + no-global-in-loop +
//   log2e folded into weights/biases + shared-rcp EW, 16 trans/lane-step):
//   256 blocks (1/CU) x 832 threads (13 waves); weights = A operand
//   (row = 4*cell + gate), h = B operand (N = batch = 16);
//   D[row=4*quad+reg][col] => lane's 4 acc regs = i,f,g,o of its cell/col;
//   h double-buffered in LDS B-layout; 1 barrier/step.

typedef _Float16 half8 __attribute__((ext_vector_type(8)));
typedef float    f32x4 __attribute__((ext_vector_type(4)));

#define TT   512
#define HID  50
#define NB   16         // batch rows per block
#define LOG2E 1.44269504f

// Weight A-fragment: lane's 8 fp16 for K-chunk `chunk`, pre-scaled by the
// gate's exp2 factor. Row m -> gate = m&3, cell = 4*wv + (m>>2).
__device__ __forceinline__ float4 make_wfrag(const float* W, int gate, int cell,
                                             int chunk, int quad, float scale) {
    half8 hv = {};
    #pragma unroll
    for (int j = 0; j < 8; ++j) {
        const int k = 32 * chunk + 8 * quad + j;
        float v = 0.0f;
        if (cell < HID && k < HID) v = W[(gate * HID + cell) * HID + k] * scale;
        hv[j] = (_Float16)v;
    }
    return __builtin_bit_cast(float4, hv);
}

// Shared-rcp LSTM cell update on pre-scaled gates:
//   a0 = -i*log2e, a1 = -f*log2e, a2 = 2g*log2e, a3 = -o*log2e.
__device__ __forceinline__ float cell_update(const f32x4 a, float& c) {
    const float ei = __builtin_exp2f(a[0]);          // e^{-i}
    const float ef = __builtin_exp2f(a[1]);          // e^{-f}
    const float eg = __builtin_exp2f(a[2]);          // e^{2g}
    const float eo = __builtin_exp2f(a[3]);          // e^{-o}
    const float itg = (eg - 1.0f) *
        __builtin_amdgcn_rcpf((1.0f + ei) * (eg + 1.0f));   // sig(i)*tanh(g)
    const float sf = __builtin_amdgcn_rcpf(1.0f + ef);      // sig(f)
    c = sf * c + itg;
    const float ec = __builtin_exp2f(c * (2.0f * LOG2E));   // e^{2c}
    return (ec - 1.0f) *
        __builtin_amdgcn_rcpf((1.0f + eo) * (ec + 1.0f));   // sig(o)*tanh(c)
}

#define PIN(f) asm volatile("" : "+v"(f.x), "+v"(f.y), "+v"(f.z), "+v"(f.w));
#define MFMA(af, b, c) __builtin_amdgcn_mfma_f32_16x16x32_f16(__builtin_bit_cast(half8, (af)), (b), (c), 0, 0, 0)

extern "C" __global__ __launch_bounds__(832, 4)
void lstm2_mfma_kernel(const float* __restrict__ x,
                       const float* __restrict__ W_ih0, const float* __restrict__ W_hh0,
                       const float* __restrict__ b_ih0, const float* __restrict__ b_hh0,
                       const float* __restrict__ W_ih1, const float* __restrict__ W_hh1,
                       const float* __restrict__ b_ih1, const float* __restrict__ b_hh1,
                       const float* __restrict__ fc_w, const float* __restrict__ fc_b,
                       float* __restrict__ out)
{
    // h-state in B-fragment layout: element (k, n) at (k>>5)*512 +
    // (((k&31)>>3)*16 + n)*8 + (k&7), k<50 (rest pad = 0).
    __shared__ _Float16 H0[2][1024];
    __shared__ _Float16 H1[2][1024];
    __shared__ float    xs[TT * NB];      // TRANSPOSED x tile: xs[t][b] (32 KB)
    __shared__ float    hfin[HID * NB];   // fp32 h1^(TT) for the FC epilogue

    const int tid  = threadIdx.x;
    const int lane = tid & 63;
    const int wv   = tid >> 6;            // wave 0..12 = gate-row tile
    const int b0   = blockIdx.x * NB;

    for (int i = tid; i < 1024; i += 832) {
        H0[0][i] = (_Float16)0.f; H0[1][i] = (_Float16)0.f;
        H1[0][i] = (_Float16)0.f; H1[1][i] = (_Float16)0.f;
    }
    // stage x transposed: read coalesced x[b][t], scatter to xs[t*NB+b] (once)
    for (int i = tid; i < NB * TT; i += 832) {
        const int b = i >> 9, t = i & 511;
        xs[t * NB + b] = x[(size_t)(b0 + b) * TT + t];
    }

    const int quad = lane >> 4;
    const int col  = lane & 15;           // batch column

    // ---- A-fragments (weights, exp2-prescaled), loaded once, pinned ----
    const int mrow  = lane & 15;
    const int gateA = mrow & 3;
    const int cellA = 4 * wv + (mrow >> 2);
    const float scA = (gateA == 2) ? 2.0f * LOG2E : -LOG2E;
    float4 A0c0 = make_wfrag(W_hh0, gateA, cellA, 0, quad, scA);
    float4 A0c1 = make_wfrag(W_hh0, gateA, cellA, 1, quad, scA);
    float4 Aic0 = make_wfrag(W_ih1, gateA, cellA, 0, quad, scA);
    float4 Aic1 = make_wfrag(W_ih1, gateA, cellA, 1, quad, scA);
    float4 Ahc0 = make_wfrag(W_hh1, gateA, cellA, 0, quad, scA);
    float4 Ahc1 = make_wfrag(W_hh1, gateA, cellA, 1, quad, scA);
    PIN(A0c0) PIN(A0c1) PIN(Aic0) PIN(Aic1) PIN(Ahc0) PIN(Ahc1)

    // ---- D-cell ownership: reg = gate, cell = 4*wv + quad, batch = col ----
    const int  cellD = 4 * wv + quad;
    const bool ewok  = (cellD < HID);
    f32x4 bias0, bias1, wx0;
    #pragma unroll
    for (int g = 0; g < 4; ++g) {
        const float s = (g == 2) ? 2.0f * LOG2E : -LOG2E;
        bias0[g] = ewok ? (b_ih0[g * HID + cellD] + b_hh0[g * HID + cellD]) * s : 0.f;
        bias1[g] = ewok ? (b_ih1[g * HID + cellD] + b_hh1[g * HID + cellD]) * s : 0.f;
        wx0[g]   = ewok ? W_ih0[g * HID + cellD] * s : 0.f;   // x rank-1 term
    }
    PIN(wx0)
    // h write-back index in B-layout for (cellD, col)
    const int wi = (cellD >> 5) * 512 + (((cellD & 31) >> 3) * 16 + col) * 8 + (cellD & 7);

    float c0 = 0.f, c1 = 0.f;
    __syncthreads();

    #pragma unroll 2
    for (int u = 0; u <= TT; ++u) {
        const int pu = u & 1, pn = pu ^ 1;

        half8 b0c0 = *(half8*)(&H0[pu][lane * 8]);
        half8 b0c1 = *(half8*)(&H0[pu][512 + lane * 8]);

        if (u != TT) {   // ---- layer-0: gates0^u + in-register EW ----
            const float xv = xs[u * NB + col];     // conflict-free broadcast
            f32x4 acc = bias0;
            #pragma unroll
            for (int g = 0; g < 4; ++g) acc[g] += wx0[g] * xv;
            acc = MFMA(A0c0, b0c0, acc);
            acc = MFMA(A0c1, b0c1, acc);
            const float h = cell_update(acc, c0);
            if (ewok) H0[pn][wi] = (_Float16)h;    // h0^{u+1}
        }
        if (u != 0) {    // ---- layer-1: gates1^{u-1} + in-register EW ----
            half8 b1c0 = *(half8*)(&H1[pn][lane * 8]);
            half8 b1c1 = *(half8*)(&H1[pn][512 + lane * 8]);
            f32x4 acc = bias1;
            acc = MFMA(Aic0, b0c0, acc);           // Wi1 . h0^u
            acc = MFMA(Aic1, b0c1, acc);
            acc = MFMA(Ahc0, b1c0, acc);           // Wh1 . h1^{u-1}
            acc = MFMA(Ahc1, b1c1, acc);
            const float h = cell_update(acc, c1);
            if (ewok) {
                H1[pu][wi] = (_Float16)h;          // h1^u
                if (u == TT) hfin[cellD * NB + col] = h;
            }
        }
        __syncthreads();
    }

    // ---------- FC epilogue: out[b] = fc_b + fc_w . h1^(TT)[b,:] ----------
    if (tid < NB) {
        float s = fc_b[0];
        for (int k = 0; k < HID; ++k)
            s += fc_w[k] * hfin[k * NB + tid];
        out[b0 + tid] = s;
    }
}

extern "C" void kernel_launch(void* const* d_in, const int* in_sizes, int n_in,
                              void* d_out, int out_size, void* d_ws, size_t ws_size,
                              hipStream_t stream) {
    (void)in_sizes; (void)n_in; (void)d_ws; (void)ws_size; (void)out_size;
    const float* x     = (const float*)d_in[0];
    const float* W_ih0 = (const float*)d_in[1];
    const float* W_hh0 = (const float*)d_in[2];
    const float* b_ih0 = (const float*)d_in[3];
    const float* b_hh0 = (const float*)d_in[4];
    const float* W_ih1 = (const float*)d_in[5];
    const float* W_hh1 = (const float*)d_in[6];
    const float* b_ih1 = (const float*)d_in[7];
    const float* b_hh1 = (const float*)d_in[8];
    const float* fc_w  = (const float*)d_in[9];
    const float* fc_b  = (const float*)d_in[10];

    dim3 grid(4096 / NB);   // 256 blocks, 1 per CU
    dim3 block(832);        // 13 waves
    lstm2_mfma_kernel<<<grid, block, 0, stream>>>(
        x, W_ih0, W_hh0, b_ih0, b_hh0,
        W_ih1, W_hh1, b_ih1, b_hh1,
        fc_w, fc_b, (float*)d_out);
}

// Round 15
// 585.251 us; speedup vs baseline: 1.0723x; 1.0216x over previous
//
#include <hip/hip_runtime.h>

// LSTMPricePredictor: B=4096, T=512, IN=1, H=50, 2 layers + FC(50->1)
// R15 = EXACT R12 structure + ONLY the shared-rcp/log2e EW (single-variable).
//   R13/R14 post-mortem: the conflict bug cost ~25 us, but the bigger
//   ~135 us regression was replacing R12's x-through-MFMA path with an
//   LDS-x + dependent-FMA chain (my "straggler" theory was wrong: the
//   in-loop global x load is L1-resident and fully covered). So: revert
//   x handling to R12 (x slot at k=50 of the B operand, W_ih0 folded into
//   the A fragment, global prefetch in-loop), keep R12's buffers/LDS size,
//   and apply only the EW improvement:
//   - log2e folded into fp16 weights/biases per gate (i,f,o x -log2e;
//     g x 2log2e) -> activations are bare v_exp_f32, no argument mul;
//   - shared-rcp cell update: 8 trans/cell (was 10), 16/lane-step.
// Structure (= R11/R12, both passed): 256 blocks (1/CU) x 832 threads
//   (13 waves); weights = A operand (row = 4*cell + gate), h = B operand
//   (N = batch = 16); D[row=4*quad+reg][col] => lane's 4 acc regs are
//   i,f,g,o of cell (4*wv+quad) for batch col; h double-buffered in LDS
//   B-layout; 1 barrier/step.

typedef _Float16 half8 __attribute__((ext_vector_type(8)));
typedef float    f32x4 __attribute__((ext_vector_type(4)));

#define TT   512
#define HID  50
#define NB   16         // batch rows per block
#define LOG2E 1.44269504f

// Weight A-fragment: lane's 8 fp16 for K-chunk `chunk`, pre-scaled by the
// gate's exp2 factor. Row m -> gate = m&3, cell = 4*wv + (m>>2).
// W is (200 x 50): element [gate*50+cell][k]. Layer-0 folds W_ih0 at k==50
// (the x slot), same scale.
__device__ __forceinline__ float4 make_wfrag(const float* W, const float* Wx,
                                             int gate, int cell, int chunk,
                                             int quad, bool foldx, float scale) {
    half8 hv = {};
    #pragma unroll
    for (int j = 0; j < 8; ++j) {
        const int k = 32 * chunk + 8 * quad + j;
        float v = 0.0f;
        if (cell < HID) {
            if (k < HID)                 v = W[(gate * HID + cell) * HID + k] * scale;
            else if (foldx && k == HID)  v = Wx[gate * HID + cell] * scale;
        }
        hv[j] = (_Float16)v;
    }
    return __builtin_bit_cast(float4, hv);
}

// Shared-rcp LSTM cell update on pre-scaled gates:
//   a0 = -i*log2e, a1 = -f*log2e, a2 = 2g*log2e, a3 = -o*log2e.
__device__ __forceinline__ float cell_update(const f32x4 a, float& c) {
    const float ei = __builtin_exp2f(a[0]);          // e^{-i}
    const float ef = __builtin_exp2f(a[1]);          // e^{-f}
    const float eg = __builtin_exp2f(a[2]);          // e^{2g}
    const float eo = __builtin_exp2f(a[3]);          // e^{-o}
    const float itg = (eg - 1.0f) *
        __builtin_amdgcn_rcpf((1.0f + ei) * (eg + 1.0f));   // sig(i)*tanh(g)
    const float sf = __builtin_amdgcn_rcpf(1.0f + ef);      // sig(f)
    c = sf * c + itg;
    const float ec = __builtin_exp2f(c * (2.0f * LOG2E));   // e^{2c}
    return (ec - 1.0f) *
        __builtin_amdgcn_rcpf((1.0f + eo) * (ec + 1.0f));   // sig(o)*tanh(c)
}

#define PIN(f) asm volatile("" : "+v"(f.x), "+v"(f.y), "+v"(f.z), "+v"(f.w));
#define MFMA(af, b, c) __builtin_amdgcn_mfma_f32_16x16x32_f16(__builtin_bit_cast(half8, (af)), (b), (c), 0, 0, 0)

extern "C" __global__ __launch_bounds__(832, 4)
void lstm2_mfma_kernel(const float* __restrict__ x,
                       const float* __restrict__ W_ih0, const float* __restrict__ W_hh0,
                       const float* __restrict__ b_ih0, const float* __restrict__ b_hh0,
                       const float* __restrict__ W_ih1, const float* __restrict__ W_hh1,
                       const float* __restrict__ b_ih1, const float* __restrict__ b_hh1,
                       const float* __restrict__ fc_w, const float* __restrict__ fc_b,
                       float* __restrict__ out)
{
    // h-state in B-fragment layout: element (k, n) at (k>>5)*512 +
    // (((k&31)>>3)*16 + n)*8 + (k&7). k<50 = h, k==50 = x slot (H0 only).
    __shared__ _Float16 H0[2][1024];
    __shared__ _Float16 H1[2][1024];
    __shared__ float    hfin[HID * NB];   // fp32 h1^(TT) for the FC epilogue

    const int tid  = threadIdx.x;
    const int lane = tid & 63;
    const int wv   = tid >> 6;            // wave 0..12 = gate-row tile
    const int b0   = blockIdx.x * NB;

    for (int i = tid; i < 1024; i += 832) {
        H0[0][i] = (_Float16)0.f; H0[1][i] = (_Float16)0.f;
        H1[0][i] = (_Float16)0.f; H1[1][i] = (_Float16)0.f;
    }

    const int quad = lane >> 4;
    const int col  = lane & 15;           // batch column

    // ---- A-fragments (weights, exp2-prescaled), loaded once, pinned ----
    const int mrow  = lane & 15;          // A-row within tile
    const int gateA = mrow & 3;
    const int cellA = 4 * wv + (mrow >> 2);
    const float scA = (gateA == 2) ? 2.0f * LOG2E : -LOG2E;
    float4 A0c0 = make_wfrag(W_hh0, W_ih0, gateA, cellA, 0, quad, true,  scA);
    float4 A0c1 = make_wfrag(W_hh0, W_ih0, gateA, cellA, 1, quad, true,  scA);
    float4 Aic0 = make_wfrag(W_ih1, W_ih1, gateA, cellA, 0, quad, false, scA);
    float4 Aic1 = make_wfrag(W_ih1, W_ih1, gateA, cellA, 1, quad, false, scA);
    float4 Ahc0 = make_wfrag(W_hh1, W_hh1, gateA, cellA, 0, quad, false, scA);
    float4 Ahc1 = make_wfrag(W_hh1, W_hh1, gateA, cellA, 1, quad, false, scA);
    PIN(A0c0) PIN(A0c1) PIN(Aic0) PIN(Aic1) PIN(Ahc0) PIN(Ahc1)

    // ---- D-cell ownership: reg = gate, cell = 4*wv + quad, batch = col ----
    const int  cellD = 4 * wv + quad;
    const bool ewok  = (cellD < HID);
    f32x4 bias0, bias1;
    #pragma unroll
    for (int g = 0; g < 4; ++g) {
        const float s = (g == 2) ? 2.0f * LOG2E : -LOG2E;
        bias0[g] = ewok ? (b_ih0[g * HID + cellD] + b_hh0[g * HID + cellD]) * s : 0.f;
        bias1[g] = ewok ? (b_ih1[g * HID + cellD] + b_hh1[g * HID + cellD]) * s : 0.f;
    }
    // h write-back index in B-layout for (cellD, col)
    const int wi = (cellD >> 5) * 512 + (((cellD & 31) >> 3) * 16 + col) * 8 + (cellD & 7);

    // x_0 into H0[0]'s x slot: k=50 -> chunk1, quad'=2, j=2
    if (tid < NB) H0[0][512 + (32 + tid) * 8 + 2] = (_Float16)x[(size_t)(b0 + tid) * TT];

    float c0 = 0.f, c1 = 0.f;
    __syncthreads();

    #pragma unroll 2
    for (int u = 0; u <= TT; ++u) {
        const int pu = u & 1, pn = pu ^ 1;

        half8 b0c0 = *(half8*)(&H0[pu][lane * 8]);
        half8 b0c1 = *(half8*)(&H0[pu][512 + lane * 8]);

        float xr = 0.f;
        if (tid < NB && (u + 1) < TT)
            xr = x[(size_t)(b0 + tid) * TT + u + 1];   // issue early (L1-resident)

        if (u != TT) {   // ---- layer-0: gates0^u + in-register EW ----
            f32x4 acc = bias0;
            acc = MFMA(A0c0, b0c0, acc);
            acc = MFMA(A0c1, b0c1, acc);               // x slot k=50 included
            const float h = cell_update(acc, c0);
            if (ewok) H0[pn][wi] = (_Float16)h;        // h0^{u+1}
        }
        if (u != 0) {    // ---- layer-1: gates1^{u-1} + in-register EW ----
            half8 b1c0 = *(half8*)(&H1[pn][lane * 8]);
            half8 b1c1 = *(half8*)(&H1[pn][512 + lane * 8]);
            f32x4 acc = bias1;
            acc = MFMA(Aic0, b0c0, acc);               // Wi1 . h0^u
            acc = MFMA(Aic1, b0c1, acc);               // (x slot hits zero rows)
            acc = MFMA(Ahc0, b1c0, acc);               // Wh1 . h1^{u-1}
            acc = MFMA(Ahc1, b1c1, acc);
            const float h = cell_update(acc, c1);
            if (ewok) {
                H1[pu][wi] = (_Float16)h;              // h1^u
                if (u == TT) hfin[cellD * NB + col] = h;
            }
        }
        if (tid < NB && (u + 1) < TT)
            H0[pn][512 + (32 + tid) * 8 + 2] = (_Float16)xr;   // x_{u+1} slot
        __syncthreads();
    }

    // ---------- FC epilogue: out[b] = fc_b + fc_w . h1^(TT)[b,:] ----------
    if (tid < NB) {
        float s = fc_b[0];
        for (int k = 0; k < HID; ++k)
            s += fc_w[k] * hfin[k * NB + tid];
        out[b0 + tid] = s;
    }
}

extern "C" void kernel_launch(void* const* d_in, const int* in_sizes, int n_in,
                              void* d_out, int out_size, void* d_ws, size_t ws_size,
                              hipStream_t stream) {
    (void)in_sizes; (void)n_in; (void)d_ws; (void)ws_size; (void)out_size;
    const float* x     = (const float*)d_in[0];
    const float* W_ih0 = (const float*)d_in[1];
    const float* W_hh0 = (const float*)d_in[2];
    const float* b_ih0 = (const float*)d_in[3];
    const float* b_hh0 = (const float*)d_in[4];
    const float* W_ih1 = (const float*)d_in[5];
    const float* W_hh1 = (const float*)d_in[6];
    const float* b_ih1 = (const float*)d_in[7];
    const float* b_hh1 = (const float*)d_in[8];
    const float* fc_w  = (const float*)d_in[9];
    const float* fc_b  = (const float*)d_in[10];

    dim3 grid(4096 / NB);   // 256 blocks, 1 per CU
    dim3 block(832);        // 13 waves
    lstm2_mfma_kernel<<<grid, block, 0, stream>>>(
        x, W_ih0, W_hh0, b_ih0, b_hh0,
        W_ih1, W_hh1, b_ih1, b_hh1,
        fc_w, fc_b, (float*)d_out);
}

// Round 16
// 414.494 us; speedup vs baseline: 1.5141x; 1.4120x over previous
//
#include <hip/hip_runtime.h>

// LSTMPricePredictor: B=4096, T=512, IN=1, H=50, 2 layers + FC(50->1)
// R16 = R15 with __builtin_exp2f -> __builtin_amdgcn_exp2f (raw v_exp_f32).
//   R15 post-mortem (563 us, REGRESSION vs R12's 447 despite fewer trans
//   ops): strict llvm.exp2.f32 lowering emits a denormal-range GUARD
//   (~5-6 VALU: cmp/cndmask/scale/fixup) around every v_exp_f32 because
//   non-fast-math exp2 must handle args < -126. 10 guarded exp2/lane-step
//   = +400 cyc/SIMD/step -- exactly the observed VALU increase (and most
//   of R13's mystery regression). Our exp2 args are |a| <= ~45, so the raw
//   hardware instruction is bit-identical on our range.
// Everything else identical to R15 (passed, absmax 4.9e-4):
//   256 blocks (1/CU) x 832 threads (13 waves); weights = A operand
//   (row = 4*cell + gate, log2e pre-folded); h = B operand (N = batch=16);
//   x through MFMA k=50 slot; D[row=4*quad+reg][col] => lane's 4 acc regs
//   = i,f,g,o of cell (4*wv+quad) for batch col; shared-rcp EW in-register;
//   h double-buffered in LDS B-layout; 1 barrier/step.

typedef _Float16 half8 __attribute__((ext_vector_type(8)));
typedef float    f32x4 __attribute__((ext_vector_type(4)));

#define TT   512
#define HID  50
#define NB   16         // batch rows per block
#define LOG2E 1.44269504f

// Weight A-fragment: lane's 8 fp16 for K-chunk `chunk`, pre-scaled by the
// gate's exp2 factor. Row m -> gate = m&3, cell = 4*wv + (m>>2).
// W is (200 x 50): element [gate*50+cell][k]. Layer-0 folds W_ih0 at k==50
// (the x slot), same scale.
__device__ __forceinline__ float4 make_wfrag(const float* W, const float* Wx,
                                             int gate, int cell, int chunk,
                                             int quad, bool foldx, float scale) {
    half8 hv = {};
    #pragma unroll
    for (int j = 0; j < 8; ++j) {
        const int k = 32 * chunk + 8 * quad + j;
        float v = 0.0f;
        if (cell < HID) {
            if (k < HID)                 v = W[(gate * HID + cell) * HID + k] * scale;
            else if (foldx && k == HID)  v = Wx[gate * HID + cell] * scale;
        }
        hv[j] = (_Float16)v;
    }
    return __builtin_bit_cast(float4, hv);
}

// Shared-rcp LSTM cell update on pre-scaled gates, RAW hardware exp2:
//   a0 = -i*log2e, a1 = -f*log2e, a2 = 2g*log2e, a3 = -o*log2e.
// All exp2 args are |a| <= ~45 (weight-init bound) -- no denormal guards needed.
__device__ __forceinline__ float cell_update(const f32x4 a, float& c) {
    const float ei = __builtin_amdgcn_exp2f(a[0]);   // e^{-i}
    const float ef = __builtin_amdgcn_exp2f(a[1]);   // e^{-f}
    const float eg = __builtin_amdgcn_exp2f(a[2]);   // e^{2g}
    const float eo = __builtin_amdgcn_exp2f(a[3]);   // e^{-o}
    const float itg = (eg - 1.0f) *
        __builtin_amdgcn_rcpf((1.0f + ei) * (eg + 1.0f));   // sig(i)*tanh(g)
    const float sf = __builtin_amdgcn_rcpf(1.0f + ef);      // sig(f)
    c = sf * c + itg;
    const float ec = __builtin_amdgcn_exp2f(c * (2.0f * LOG2E));  // e^{2c}
    return (ec - 1.0f) *
        __builtin_amdgcn_rcpf((1.0f + eo) * (ec + 1.0f));   // sig(o)*tanh(c)
}

#define PIN(f) asm volatile("" : "+v"(f.x), "+v"(f.y), "+v"(f.z), "+v"(f.w));
#define MFMA(af, b, c) __builtin_amdgcn_mfma_f32_16x16x32_f16(__builtin_bit_cast(half8, (af)), (b), (c), 0, 0, 0)

extern "C" __global__ __launch_bounds__(832, 4)
void lstm2_mfma_kernel(const float* __restrict__ x,
                       const float* __restrict__ W_ih0, const float* __restrict__ W_hh0,
                       const float* __restrict__ b_ih0, const float* __restrict__ b_hh0,
                       const float* __restrict__ W_ih1, const float* __restrict__ W_hh1,
                       const float* __restrict__ b_ih1, const float* __restrict__ b_hh1,
                       const float* __restrict__ fc_w, const float* __restrict__ fc_b,
                       float* __restrict__ out)
{
    // h-state in B-fragment layout: element (k, n) at (k>>5)*512 +
    // (((k&31)>>3)*16 + n)*8 + (k&7). k<50 = h, k==50 = x slot (H0 only).
    __shared__ _Float16 H0[2][1024];
    __shared__ _Float16 H1[2][1024];
    __shared__ float    hfin[HID * NB];   // fp32 h1^(TT) for the FC epilogue

    const int tid  = threadIdx.x;
    const int lane = tid & 63;
    const int wv   = tid >> 6;            // wave 0..12 = gate-row tile
    const int b0   = blockIdx.x * NB;

    for (int i = tid; i < 1024; i += 832) {
        H0[0][i] = (_Float16)0.f; H0[1][i] = (_Float16)0.f;
        H1[0][i] = (_Float16)0.f; H1[1][i] = (_Float16)0.f;
    }

    const int quad = lane >> 4;
    const int col  = lane & 15;           // batch column

    // ---- A-fragments (weights, exp2-prescaled), loaded once, pinned ----
    const int mrow  = lane & 15;          // A-row within tile
    const int gateA = mrow & 3;
    const int cellA = 4 * wv + (mrow >> 2);
    const float scA = (gateA == 2) ? 2.0f * LOG2E : -LOG2E;
    float4 A0c0 = make_wfrag(W_hh0, W_ih0, gateA, cellA, 0, quad, true,  scA);
    float4 A0c1 = make_wfrag(W_hh0, W_ih0, gateA, cellA, 1, quad, true,  scA);
    float4 Aic0 = make_wfrag(W_ih1, W_ih1, gateA, cellA, 0, quad, false, scA);
    float4 Aic1 = make_wfrag(W_ih1, W_ih1, gateA, cellA, 1, quad, false, scA);
    float4 Ahc0 = make_wfrag(W_hh1, W_hh1, gateA, cellA, 0, quad, false, scA);
    float4 Ahc1 = make_wfrag(W_hh1, W_hh1, gateA, cellA, 1, quad, false, scA);
    PIN(A0c0) PIN(A0c1) PIN(Aic0) PIN(Aic1) PIN(Ahc0) PIN(Ahc1)

    // ---- D-cell ownership: reg = gate, cell = 4*wv + quad, batch = col ----
    const int  cellD = 4 * wv + quad;
    const bool ewok  = (cellD < HID);
    f32x4 bias0, bias1;
    #pragma unroll
    for (int g = 0; g < 4; ++g) {
        const float s = (g == 2) ? 2.0f * LOG2E : -LOG2E;
        bias0[g] = ewok ? (b_ih0[g * HID + cellD] + b_hh0[g * HID + cellD]) * s : 0.f;
        bias1[g] = ewok ? (b_ih1[g * HID + cellD] + b_hh1[g * HID + cellD]) * s : 0.f;
    }
    // h write-back index in B-layout for (cellD, col)
    const int wi = (cellD >> 5) * 512 + (((cellD & 31) >> 3) * 16 + col) * 8 + (cellD & 7);

    // x_0 into H0[0]'s x slot: k=50 -> chunk1, quad'=2, j=2
    if (tid < NB) H0[0][512 + (32 + tid) * 8 + 2] = (_Float16)x[(size_t)(b0 + tid) * TT];

    float c0 = 0.f, c1 = 0.f;
    __syncthreads();

    #pragma unroll 2
    for (int u = 0; u <= TT; ++u) {
        const int pu = u & 1, pn = pu ^ 1;

        half8 b0c0 = *(half8*)(&H0[pu][lane * 8]);
        half8 b0c1 = *(half8*)(&H0[pu][512 + lane * 8]);

        float xr = 0.f;
        if (tid < NB && (u + 1) < TT)
            xr = x[(size_t)(b0 + tid) * TT + u + 1];   // issue early (L1-resident)

        if (u != TT) {   // ---- layer-0: gates0^u + in-register EW ----
            f32x4 acc = bias0;
            acc = MFMA(A0c0, b0c0, acc);
            acc = MFMA(A0c1, b0c1, acc);               // x slot k=50 included
            const float h = cell_update(acc, c0);
            if (ewok) H0[pn][wi] = (_Float16)h;        // h0^{u+1}
        }
        if (u != 0) {    // ---- layer-1: gates1^{u-1} + in-register EW ----
            half8 b1c0 = *(half8*)(&H1[pn][lane * 8]);
            half8 b1c1 = *(half8*)(&H1[pn][512 + lane * 8]);
            f32x4 acc = bias1;
            acc = MFMA(Aic0, b0c0, acc);               // Wi1 . h0^u
            acc = MFMA(Aic1, b0c1, acc);               // (x slot hits zero rows)
            acc = MFMA(Ahc0, b1c0, acc);               // Wh1 . h1^{u-1}
            acc = MFMA(Ahc1, b1c1, acc);
            const float h = cell_update(acc, c1);
            if (ewok) {
                H1[pu][wi] = (_Float16)h;              // h1^u
                if (u == TT) hfin[cellD * NB + col] = h;
            }
        }
        if (tid < NB && (u + 1) < TT)
            H0[pn][512 + (32 + tid) * 8 + 2] = (_Float16)xr;   // x_{u+1} slot
        __syncthreads();
    }

    // ---------- FC epilogue: out[b] = fc_b + fc_w . h1^(TT)[b,:] ----------
    if (tid < NB) {
        float s = fc_b[0];
        for (int k = 0; k < HID; ++k)
            s += fc_w[k] * hfin[k * NB + tid];
        out[b0 + tid] = s;
    }
}

extern "C" void kernel_launch(void* const* d_in, const int* in_sizes, int n_in,
                              void* d_out, int out_size, void* d_ws, size_t ws_size,
                              hipStream_t stream) {
    (void)in_sizes; (void)n_in; (void)d_ws; (void)ws_size; (void)out_size;
    const float* x     = (const float*)d_in[0];
    const float* W_ih0 = (const float*)d_in[1];
    const float* W_hh0 = (const float*)d_in[2];
    const float* b_ih0 = (const float*)d_in[3];
    const float* b_hh0 = (const float*)d_in[4];
    const float* W_ih1 = (const float*)d_in[5];
    const float* W_hh1 = (const float*)d_in[6];
    const float* b_ih1 = (const float*)d_in[7];
    const float* b_hh1 = (const float*)d_in[8];
    const float* fc_w  = (const float*)d_in[9];
    const float* fc_b  = (const float*)d_in[10];

    dim3 grid(4096 / NB);   // 256 blocks, 1 per CU
    dim3 block(832);        // 13 waves
    lstm2_mfma_kernel<<<grid, block, 0, stream>>>(
        x, W_ih0, W_hh0, b_ih0, b_hh0,
        W_ih1, W_hh1, b_ih1, b_hh1,
        fc_w, fc_b, (float*)d_out);
}